// Round 3
// baseline (793.298 us; speedup 1.0000x reference)
//
#include <hip/hip_runtime.h>

#define T_LEN 512
#define B_SZ  256
#define N_ST  128

// ws layout (floats): [0..255] logZ_b ; [256..511] score_b ; [512..767] lens (int)

__global__ __launch_bounds__(64) void lengths_kernel(const unsigned char* __restrict__ mask_raw,
                                                     int* __restrict__ lens) {
    int b = blockIdx.x;   // 256 blocks
    int l = threadIdx.x;  // 64 threads
    // Detect mask encoding (mask[0][*] is always true since lengths >= T/2):
    // u8 : byte[1]=mask[0][1]=1 ; i32: bytes 1,2 = 0 ; f32: 1.0f -> byte[2]=0x80
    unsigned char b1 = mask_raw[1], b2 = mask_raw[2];
    int mode = (b1 != 0) ? 0 : ((b2 != 0) ? 2 : 1);
    int cnt = 0;
    if (mode == 0) {
        #pragma unroll
        for (int k = 0; k < 8; ++k) cnt += (mask_raw[(l * 8 + k) * B_SZ + b] != 0);
    } else if (mode == 1) {
        const int* m = (const int*)mask_raw;
        #pragma unroll
        for (int k = 0; k < 8; ++k) cnt += (m[(l * 8 + k) * B_SZ + b] != 0);
    } else {
        const float* m = (const float*)mask_raw;
        #pragma unroll
        for (int k = 0; k < 8; ++k) cnt += (m[(l * 8 + k) * B_SZ + b] != 0.0f);
    }
    #pragma unroll
    for (int off = 1; off < 64; off <<= 1) cnt += __shfl_xor(cnt, off);
    if (l == 0) lens[b] = cnt;
}

// ONE wave per block: no __syncthreads anywhere in the t-loop. Lane l owns
// columns l and l+64; E for both columns lives in 256 VGPRs; `a` ping-pongs
// through LDS with wave-internal in-order DS semantics (lgkmcnt only).
__global__ __launch_bounds__(64, 1) void forward_kernel(
        const float* __restrict__ emit,
        const float* __restrict__ trans,
        const float* __restrict__ strans,
        const float* __restrict__ etrans,
        const int* __restrict__ lens,
        float* __restrict__ logZ_out) {
    const int b  = blockIdx.x;
    const int l  = threadIdx.x;   // 0..63
    const int j0 = l;
    const int j1 = l + 64;

    __shared__ float bufA[N_ST];
    __shared__ float bufB[N_ST];

    // E[i][j] = exp(trans[i][j]) for this lane's two columns: 256 VGPRs.
    float E0[N_ST], E1[N_ST];
    #pragma unroll
    for (int i = 0; i < N_ST; ++i) {
        E0[i] = __expf(trans[i * N_ST + j0]);
        E1[i] = __expf(trans[i * N_ST + j1]);
    }

    const int len = lens[b];
    const float* eb = emit + (size_t)b * N_ST;
    const size_t TS = (size_t)B_SZ * N_ST;

    // a = exp(alpha - Macc), normalized each step by a[0] (exact bookkeeping).
    float a0 = __expf(strans[j0] + eb[j0]);
    float a1 = __expf(strans[j1] + eb[j1]);
    bufA[j0] = a0;
    bufA[j1] = a1;
    float Macc = 0.0f;
    float* cur = bufA;
    float* nxt = bufB;
    float e0 = eb[TS + j0];   // emit[1] prefetch (len >= 256 always)
    float e1 = eb[TS + j1];

    for (int t = 1; t < len; ++t) {
        const size_t tn = (size_t)((t + 1 < len) ? t + 1 : len - 1) * TS;
        const float en0 = eb[tn + j0];    // next-step prefetch, off critical path
        const float en1 = eb[tn + j1];
        const float ee0 = __expf(e0);
        const float ee1 = __expf(e1);

        // s_j = sum_i a_i * E[i][j], two columns, 8 independent chains
        float s00 = 0.f, s01 = 0.f, s02 = 0.f, s03 = 0.f;
        float s10 = 0.f, s11 = 0.f, s12 = 0.f, s13 = 0.f;
        const float4* a4 = (const float4*)cur;
        float rcp0 = 0.f;
        #pragma unroll
        for (int k = 0; k < 32; ++k) {
            float4 av = a4[k];                      // broadcast read, conflict-free
            if (k == 0) rcp0 = __builtin_amdgcn_rcpf(av.x);  // uniform 1/a[0]
            s00 = fmaf(av.x, E0[4 * k + 0], s00);
            s10 = fmaf(av.x, E1[4 * k + 0], s10);
            s01 = fmaf(av.y, E0[4 * k + 1], s01);
            s11 = fmaf(av.y, E1[4 * k + 1], s11);
            s02 = fmaf(av.z, E0[4 * k + 2], s02);
            s12 = fmaf(av.z, E1[4 * k + 2], s12);
            s03 = fmaf(av.w, E0[4 * k + 3], s03);
            s13 = fmaf(av.w, E1[4 * k + 3], s13);
        }
        const float s0 = (s00 + s01) + (s02 + s03);
        const float s1 = (s10 + s11) + (s12 + s13);
        Macc -= __logf(rcp0);          // off critical path
        a0 = ee0 * s0 * rcp0;          // a' = exp(emit) * (a . E) / a[0]
        a1 = ee1 * s1 * rcp0;
        nxt[j0] = a0;
        nxt[j1] = a1;
        float* tmp = cur; cur = nxt; nxt = tmp;
        e0 = en0; e1 = en1;
        // no barrier: single wave, DS ops complete in order
    }

    // logZ_b = Macc + log( sum_j a_j * exp(etrans_j) ) ; a values still in regs
    float v = a0 * __expf(etrans[j0]) + a1 * __expf(etrans[j1]);
    #pragma unroll
    for (int off = 1; off < 64; off <<= 1) v += __shfl_xor(v, off);
    if (l == 0) logZ_out[b] = Macc + __logf(v);
}

__global__ __launch_bounds__(128) void score_kernel(
        const float* __restrict__ emit,
        const int* __restrict__ target,
        const float* __restrict__ trans,
        const float* __restrict__ strans,
        const float* __restrict__ etrans,
        const int* __restrict__ lens,
        float* __restrict__ score_out) {
    const int b   = blockIdx.x;
    const int tid = threadIdx.x;  // 128
    const int len = lens[b];
    float local = 0.f;
    for (int t = tid; t < len; t += 128) {
        int tgt = target[t * B_SZ + b];
        float v = emit[(size_t)t * (B_SZ * N_ST) + b * N_ST + tgt];
        if (t > 0) v += trans[target[(t - 1) * B_SZ + b] * N_ST + tgt];
        local += v;
    }
    if (tid == 0) {
        local += strans[target[b]];
        local += etrans[target[(len - 1) * B_SZ + b]];
    }
    #pragma unroll
    for (int off = 1; off < 64; off <<= 1) local += __shfl_xor(local, off);
    __shared__ float partial[2];
    if ((tid & 63) == 0) partial[tid >> 6] = local;
    __syncthreads();
    if (tid == 0) score_out[b] = partial[0] + partial[1];
}

__global__ __launch_bounds__(256) void finalize_kernel(
        const float* __restrict__ logZ,
        const float* __restrict__ score,
        float* __restrict__ out) {
    int tid = threadIdx.x;  // 256
    float v = logZ[tid] - score[tid];
    #pragma unroll
    for (int off = 1; off < 64; off <<= 1) v += __shfl_xor(v, off);
    __shared__ float p[4];
    if ((tid & 63) == 0) p[tid >> 6] = v;
    __syncthreads();
    if (tid == 0) out[0] = (p[0] + p[1] + p[2] + p[3]) / 256.0f;
}

extern "C" void kernel_launch(void* const* d_in, const int* in_sizes, int n_in,
                              void* d_out, int out_size, void* d_ws, size_t ws_size,
                              hipStream_t stream) {
    const float*         emit   = (const float*)d_in[0];
    const int*           target = (const int*)d_in[1];
    const unsigned char* mask   = (const unsigned char*)d_in[2];
    const float*         trans  = (const float*)d_in[3];
    const float*         strans = (const float*)d_in[4];
    const float*         etrans = (const float*)d_in[5];

    float* ws     = (float*)d_ws;
    float* logZb  = ws;            // 256
    float* scoreb = ws + 256;      // 256
    int*   lens   = (int*)(ws + 512);

    lengths_kernel<<<B_SZ, 64, 0, stream>>>(mask, lens);
    forward_kernel<<<B_SZ, 64, 0, stream>>>(emit, trans, strans, etrans, lens, logZb);
    score_kernel<<<B_SZ, 128, 0, stream>>>(emit, target, trans, strans, etrans, lens, scoreb);
    finalize_kernel<<<1, 256, 0, stream>>>(logZb, scoreb, (float*)d_out);
}

// Round 4
// 239.011 us; speedup vs baseline: 3.3191x; 3.3191x over previous
//
#include <hip/hip_runtime.h>

#define T_LEN 512
#define B_SZ  256
#define N_ST  128

#if defined(__has_builtin)
# if __has_builtin(__builtin_amdgcn_fdot2_f32_bf16)
#  define HAVE_DOT2 1
# endif
#endif
#ifndef HAVE_DOT2
# define HAVE_DOT2 0
#endif

typedef unsigned int uint32;
typedef __bf16 bf16x2 __attribute__((ext_vector_type(2)));

__device__ __forceinline__ uint32 bf16rn(float f) {   // round-to-nearest-even bf16 (no NaNs expected)
    uint32 u = __builtin_bit_cast(uint32, f);
    u += 0x7fffu + ((u >> 16) & 1u);
    return u >> 16;
}

// c += a.lo*b.lo + a.hi*b.hi  (bf16 pairs, f32 accumulate)
__device__ __forceinline__ float dot2b(uint32 a, uint32 b, float c) {
#if HAVE_DOT2
    return __builtin_amdgcn_fdot2_f32_bf16(__builtin_bit_cast(bf16x2, a),
                                           __builtin_bit_cast(bf16x2, b), c, false);
#else
    float alo = __builtin_bit_cast(float, a << 16);
    float ahi = __builtin_bit_cast(float, a & 0xffff0000u);
    float blo = __builtin_bit_cast(float, b << 16);
    float bhi = __builtin_bit_cast(float, b & 0xffff0000u);
    return fmaf(ahi, bhi, fmaf(alo, blo, c));
#endif
}

// ws layout (floats): [0..255] logZ_b ; [256..511] score_b ; [512..767] lens (int)

__global__ __launch_bounds__(64) void lengths_kernel(const unsigned char* __restrict__ mask_raw,
                                                     int* __restrict__ lens) {
    int b = blockIdx.x;   // 256 blocks
    int l = threadIdx.x;  // 64 threads
    // Detect mask encoding (mask[0][*] always true since lengths >= T/2):
    // u8: byte[1]=1 ; i32: bytes1,2=0 ; f32: 1.0f -> byte[2]=0x80
    unsigned char b1 = mask_raw[1], b2 = mask_raw[2];
    int mode = (b1 != 0) ? 0 : ((b2 != 0) ? 2 : 1);
    int cnt = 0;
    if (mode == 0) {
        #pragma unroll
        for (int k = 0; k < 8; ++k) cnt += (mask_raw[(l * 8 + k) * B_SZ + b] != 0);
    } else if (mode == 1) {
        const int* m = (const int*)mask_raw;
        #pragma unroll
        for (int k = 0; k < 8; ++k) cnt += (m[(l * 8 + k) * B_SZ + b] != 0);
    } else {
        const float* m = (const float*)mask_raw;
        #pragma unroll
        for (int k = 0; k < 8; ++k) cnt += (m[(l * 8 + k) * B_SZ + b] != 0.0f);
    }
    #pragma unroll
    for (int off = 1; off < 64; off <<= 1) cnt += __shfl_xor(cnt, off);
    if (l == 0) lens[b] = cnt;
}

// Single wave per block, no barriers. Lane l owns columns l and l+64.
// E (=exp(trans)) packed as bf16 pairs: 2 cols x 64 dwords = 128 VGPRs (FITS).
// `a` vector lives in LDS as bf16[128]; per step each lane reads all of it
// (16x ds_read_b128 broadcast) and does 128 v_dot2_f32_bf16.
__global__ __launch_bounds__(64, 1) void forward_kernel(
        const float* __restrict__ emit,
        const float* __restrict__ trans,
        const float* __restrict__ strans,
        const float* __restrict__ etrans,
        const int* __restrict__ lens,
        float* __restrict__ logZ_out) {
    const int b  = blockIdx.x;
    const int l  = threadIdx.x;   // 0..63
    const int j0 = l;
    const int j1 = l + 64;

    __shared__ alignas(16) unsigned short a16[N_ST];

    // Pack E columns j0,j1 as bf16 pairs over i: EA[p] = (E[2p][j0], E[2p+1][j0])
    uint32 EA[64], EB[64];
    #pragma unroll
    for (int p = 0; p < 64; ++p) {
        float ea0 = __expf(trans[(2 * p)     * N_ST + j0]);
        float ea1 = __expf(trans[(2 * p + 1) * N_ST + j0]);
        float eb0 = __expf(trans[(2 * p)     * N_ST + j1]);
        float eb1 = __expf(trans[(2 * p + 1) * N_ST + j1]);
        EA[p] = bf16rn(ea0) | (bf16rn(ea1) << 16);
        EB[p] = bf16rn(eb0) | (bf16rn(eb1) << 16);
    }

    const int len = lens[b];
    const float* eb = emit + (size_t)b * N_ST;
    const size_t TS = (size_t)B_SZ * N_ST;

    float aA = __expf(strans[j0] + eb[j0]);
    float aB = __expf(strans[j1] + eb[j1]);
    a16[j0] = (unsigned short)bf16rn(aA);
    a16[j1] = (unsigned short)bf16rn(aB);
    float Macc = 0.0f;
    float e0 = eb[TS + j0];   // emit[1] prefetch (len >= T/2 >= 2 always)
    float e1 = eb[TS + j1];

    for (int t = 1; t < len; ++t) {
        const size_t tn = (size_t)((t + 1 < len) ? t + 1 : len - 1) * TS;
        const float en0 = eb[tn + j0];     // next-step prefetch
        const float en1 = eb[tn + j1];
        const float eeA = __expf(e0);
        const float eeB = __expf(e1);

        float A0 = 0.f, A1 = 0.f, A2 = 0.f, A3 = 0.f;
        float B0 = 0.f, B1 = 0.f, B2 = 0.f, B3 = 0.f;
        #pragma unroll
        for (int q = 0; q < 16; ++q) {
            uint4 w;  // alias-safe LDS read (memcpy -> ds_read_b128, ordered vs ushort writes)
            __builtin_memcpy(&w, (const char*)a16 + 16 * q, 16);
            A0 = dot2b(w.x, EA[4 * q + 0], A0);  B0 = dot2b(w.x, EB[4 * q + 0], B0);
            A1 = dot2b(w.y, EA[4 * q + 1], A1);  B1 = dot2b(w.y, EB[4 * q + 1], B1);
            A2 = dot2b(w.z, EA[4 * q + 2], A2);  B2 = dot2b(w.z, EB[4 * q + 2], B2);
            A3 = dot2b(w.w, EA[4 * q + 3], A3);  B3 = dot2b(w.w, EB[4 * q + 3], B3);
        }
        const float rA = (A0 + A1) + (A2 + A3);
        const float rB = (B0 + B1) + (B2 + B3);
        const float r0   = __shfl(rA, 0);              // uniform normalizer = r of column 0
        const float rcp0 = __builtin_amdgcn_rcpf(r0);
        Macc -= __logf(rcp0);                          // exact bookkeeping for the applied scale
        aA = eeA * rA * rcp0;                          // a' = exp(emit) * (a.E) / r0
        aB = eeB * rB * rcp0;
        a16[j0] = (unsigned short)bf16rn(aA);          // wave-internal DS ordering: no barrier
        a16[j1] = (unsigned short)bf16rn(aB);
        e0 = en0; e1 = en1;
    }

    // logZ_b = Macc + log( sum_j a_j * exp(etrans_j) )
    float v = aA * __expf(etrans[j0]) + aB * __expf(etrans[j1]);
    #pragma unroll
    for (int off = 1; off < 64; off <<= 1) v += __shfl_xor(v, off);
    if (l == 0) logZ_out[b] = Macc + __logf(v);
}

__global__ __launch_bounds__(128) void score_kernel(
        const float* __restrict__ emit,
        const int* __restrict__ target,
        const float* __restrict__ trans,
        const float* __restrict__ strans,
        const float* __restrict__ etrans,
        const int* __restrict__ lens,
        float* __restrict__ score_out) {
    const int b   = blockIdx.x;
    const int tid = threadIdx.x;  // 128
    const int len = lens[b];
    float local = 0.f;
    for (int t = tid; t < len; t += 128) {
        int tgt = target[t * B_SZ + b];
        float v = emit[(size_t)t * (B_SZ * N_ST) + b * N_ST + tgt];
        if (t > 0) v += trans[target[(t - 1) * B_SZ + b] * N_ST + tgt];
        local += v;
    }
    if (tid == 0) {
        local += strans[target[b]];
        local += etrans[target[(len - 1) * B_SZ + b]];
    }
    #pragma unroll
    for (int off = 1; off < 64; off <<= 1) local += __shfl_xor(local, off);
    __shared__ float partial[2];
    if ((tid & 63) == 0) partial[tid >> 6] = local;
    __syncthreads();
    if (tid == 0) score_out[b] = partial[0] + partial[1];
}

__global__ __launch_bounds__(256) void finalize_kernel(
        const float* __restrict__ logZ,
        const float* __restrict__ score,
        float* __restrict__ out) {
    int tid = threadIdx.x;  // 256
    float v = logZ[tid] - score[tid];
    #pragma unroll
    for (int off = 1; off < 64; off <<= 1) v += __shfl_xor(v, off);
    __shared__ float p[4];
    if ((tid & 63) == 0) p[tid >> 6] = v;
    __syncthreads();
    if (tid == 0) out[0] = (p[0] + p[1] + p[2] + p[3]) / 256.0f;
}

extern "C" void kernel_launch(void* const* d_in, const int* in_sizes, int n_in,
                              void* d_out, int out_size, void* d_ws, size_t ws_size,
                              hipStream_t stream) {
    const float*         emit   = (const float*)d_in[0];
    const int*           target = (const int*)d_in[1];
    const unsigned char* mask   = (const unsigned char*)d_in[2];
    const float*         trans  = (const float*)d_in[3];
    const float*         strans = (const float*)d_in[4];
    const float*         etrans = (const float*)d_in[5];

    float* ws     = (float*)d_ws;
    float* logZb  = ws;            // 256
    float* scoreb = ws + 256;      // 256
    int*   lens   = (int*)(ws + 512);

    lengths_kernel<<<B_SZ, 64, 0, stream>>>(mask, lens);
    forward_kernel<<<B_SZ, 64, 0, stream>>>(emit, trans, strans, etrans, lens, logZb);
    score_kernel<<<B_SZ, 128, 0, stream>>>(emit, target, trans, strans, etrans, lens, scoreb);
    finalize_kernel<<<1, 256, 0, stream>>>(logZb, scoreb, (float*)d_out);
}